// Round 10
// baseline (98.957 us; speedup 1.0000x reference)
//
#include <hip/hip_runtime.h>
#include <math.h>

#define NB 4
#define NV 4096
#define DIN 3072
#define HD 64
#define CAP 80

typedef unsigned short u16;
typedef unsigned int u32;

__device__ __forceinline__ float lo16(u32 u) { return __uint_as_float(u << 16); }
__device__ __forceinline__ float hi16(u32 u) { return __uint_as_float(u & 0xffff0000u); }

// ---------------- encoder stage A: partial GEMV h_partial = stim @ W1 over k-chunks
__global__ __launch_bounds__(256) void enc_a_kernel(const float* __restrict__ stim,
                                                    const float* __restrict__ W1,
                                                    float* __restrict__ part) {
  int c = blockIdx.x;           // 24 k-chunks of 128
  int b = blockIdx.y;           // 4 batches
  int t = threadIdx.x;
  int j = t & 127, h = t >> 7;  // h: which 64-k half
  int k0 = c * 128 + h * 64;
  float acc = 0.f;
#pragma unroll 8
  for (int k = 0; k < 64; ++k)
    acc += stim[b * DIN + k0 + k] * W1[(size_t)(k0 + k) * 128 + j];
  part[((b * 24 + c) * 2 + h) * 128 + j] = acc;
}

// ---------------- encoder stage B: fixed-order reduce + LN + GELU + Linear(128->64)
__global__ __launch_bounds__(128) void enc_b_kernel(
    const float* __restrict__ part, const float* __restrict__ b1,
    const float* __restrict__ lng, const float* __restrict__ lnb,
    const float* __restrict__ W2, const float* __restrict__ b2, float* __restrict__ g) {
  int b = blockIdx.x;
  int t = threadIdx.x;
  float hv = 0.f;
  for (int c = 0; c < 48; ++c) hv += part[(b * 48 + c) * 128 + t];  // deterministic order
  hv += b1[t];
  __shared__ float act[128];
  __shared__ float red[128];
  __shared__ float s_mu, s_var;
  act[t] = hv;
  red[t] = hv;
  __syncthreads();
  for (int s = 64; s > 0; s >>= 1) {
    if (t < s) red[t] += red[t + s];
    __syncthreads();
  }
  if (t == 0) s_mu = red[0] * (1.f / 128.f);
  __syncthreads();
  float dv = act[t] - s_mu;
  red[t] = dv * dv;
  __syncthreads();
  for (int s = 64; s > 0; s >>= 1) {
    if (t < s) red[t] += red[t + s];
    __syncthreads();
  }
  if (t == 0) s_var = red[0] * (1.f / 128.f);
  __syncthreads();
  float y = (act[t] - s_mu) * rsqrtf(s_var + 1e-5f) * lng[t] + lnb[t];
  act[t] = 0.5f * y * (1.f + erff(y * 0.70710678118f));  // exact GELU
  __syncthreads();
  if (t < 64) {
    float a2 = 0.f;
    for (int k = 0; k < 128; ++k) a2 += act[k] * W2[k * 64 + t];
    g[b * 64 + t] = a2 + b2[t];
  }
}

// ---------------- deterministic neighbor-list build; shuffle prefix-scan; zero-filled tail
__global__ __launch_bounds__(256) void csr_kernel(const float* __restrict__ adj,
                                                  int* __restrict__ cnt, int* __restrict__ cols) {
  int row = blockIdx.x;
  int t = threadIdx.x;
  int l = t & 63, w = t >> 6;
  __shared__ int wtot[4];
  __shared__ int stot;
  const float4* p = (const float4*)(adj + (size_t)row * NV);
  float4 v0 = p[t], v1 = p[t + 256], v2 = p[t + 512], v3 = p[t + 768];
  int c = (v0.x > 0.f) + (v0.y > 0.f) + (v0.z > 0.f) + (v0.w > 0.f) +
          (v1.x > 0.f) + (v1.y > 0.f) + (v1.z > 0.f) + (v1.w > 0.f) +
          (v2.x > 0.f) + (v2.y > 0.f) + (v2.z > 0.f) + (v2.w > 0.f) +
          (v3.x > 0.f) + (v3.y > 0.f) + (v3.z > 0.f) + (v3.w > 0.f);
  int val = c;  // inclusive prefix within wave
#pragma unroll
  for (int off = 1; off < 64; off <<= 1) {
    int tmp = __shfl_up(val, off, 64);
    if (l >= off) val += tmp;
  }
  if (l == 63) wtot[w] = val;
  __syncthreads();
  int base = 0;
  for (int i = 0; i < w; ++i) base += wtot[i];
  if (t == 255) {
    int s = base + val;
    s = s > CAP ? CAP : s;
    cnt[row] = s;
    stot = s;
  }
  int o = base + (val - c);  // exclusive global prefix
  int* cr = cols + row * CAP;
#define EMIT(vv, jj) if ((vv) > 0.f) { if (o < CAP) cr[o] = (jj); ++o; }
  int j0 = t * 4, j1 = (t + 256) * 4, j2 = (t + 512) * 4, j3 = (t + 768) * 4;
  EMIT(v0.x, j0) EMIT(v0.y, j0 + 1) EMIT(v0.z, j0 + 2) EMIT(v0.w, j0 + 3)
  EMIT(v1.x, j1) EMIT(v1.y, j1 + 1) EMIT(v1.z, j1 + 2) EMIT(v1.w, j1 + 3)
  EMIT(v2.x, j2) EMIT(v2.y, j2 + 1) EMIT(v2.z, j2 + 2) EMIT(v2.w, j2 + 3)
  EMIT(v3.x, j3) EMIT(v3.y, j3 + 1) EMIT(v3.z, j3 + 2) EMIT(v3.w, j3 + 3)
#undef EMIT
  __syncthreads();
  if (t < CAP && t >= stot) cr[t] = 0;  // valid row id; p==0 masks it in attn
}

// ---------------- fused Wh(fp32 + bf16) = x@Wg and Sk = x@Sw + sb
template <int LAYER>
__global__ __launch_bounds__(256) void whsk_kernel(
    const float* __restrict__ g, const float* __restrict__ emb, const float* __restrict__ xin,
    const float* __restrict__ Wg, const float* __restrict__ Sw, const float* __restrict__ Sb,
    float* __restrict__ Wh, u16* __restrict__ Wh16, float* __restrict__ Sk) {
  __shared__ float wg[4096];
  __shared__ float sw[4096];
  __shared__ float xs[2048];
  __shared__ float sbs[64];
  int tid = threadIdx.x;
  for (int i = tid; i < 4096; i += 256) {
    wg[i] = Wg[i];
    sw[i] = Sw[i];
  }
  if (tid < 64) sbs[tid] = Sb[tid];
  int base = blockIdx.x * 32;  // 32 rows per block; all same batch
  int b = base >> 12;
  for (int i = tid; i < 2048; i += 256) {
    int rr = i >> 6, k = i & 63;
    int grow = base + rr;
    if (LAYER == 1) {
      int n = grow & (NV - 1);
      xs[i] = g[b * 64 + k] + emb[(size_t)n * 64 + k];
    } else {
      xs[i] = xin[(size_t)grow * 64 + k];
    }
  }
  __syncthreads();
  int cidx = tid & 63, r0 = tid >> 6;
  for (int rr = r0; rr < 32; rr += 4) {
    float aw = 0.f, as = 0.f;
#pragma unroll
    for (int k = 0; k < 64; ++k) {
      float xv = xs[rr * 64 + k];
      aw += xv * wg[k * 64 + cidx];
      as += xv * sw[k * 64 + cidx];
    }
    int grow = base + rr;
    Wh[(size_t)grow * 64 + cidx] = aw;
    u32 u = __float_as_uint(aw);  // RNE bf16
    Wh16[(size_t)grow * 64 + cidx] = (u16)((u + 0x7fffu + ((u >> 16) & 1u)) >> 16);
    Sk[(size_t)grow * 64 + cidx] = as + sbs[cidx];
  }
}

// ---------------- sparse GAT attention: wave/row; ALL loads staged upfront (max MLP)
template <bool ELU1>
__global__ __launch_bounds__(256, 1) void attn_kernel(
    const float* __restrict__ Wh, const u16* __restrict__ Wh16, const float* __restrict__ Sk,
    const int* __restrict__ cnt, const int* __restrict__ cols, float* __restrict__ xout,
    const float* __restrict__ roW, const float* __restrict__ rob, float* __restrict__ out) {
  int tid = threadIdx.x;
  int lane = tid & 63;
  int w = tid >> 6;
  int wid = blockIdx.x * 4 + w;  // = b*NV + n
  int b = wid >> 12;
  int n = __builtin_amdgcn_readfirstlane(wid & (NV - 1));
  const float* whbase = Wh + (size_t)b * (NV * HD);
  const u16* w16base = Wh16 + (size_t)b * (NV * HD);
  int nn = __builtin_amdgcn_readfirstlane(cnt[n]);
  const int* cl = cols + n * CAP;
  int q = lane & 3;    // lane-in-quad
  int gq = lane >> 2;  // quad 0..15

  // ---------- issue ALL loads upfront: query + 3 score blocks + 48 PV rows + Sk ----------
  const float* qrow = whbase + n * HD;
  float4 wa0 = *(const float4*)(qrow + 8 * q);
  float4 wa1 = *(const float4*)(qrow + 8 * q + 4);
  float4 wb0 = *(const float4*)(qrow + 8 * q + 32);
  float4 wb1 = *(const float4*)(qrow + 8 * q + 36);

  int mS[3];
#pragma unroll
  for (int jb = 0; jb < 3; ++jb) mS[jb] = cl[jb * 16 + gq];  // per-lane indices
  uint4 SA[3], SB[3];
#pragma unroll
  for (int jb = 0; jb < 3; ++jb) {
    const uint4* vr = (const uint4*)(w16base + (size_t)mS[jb] * HD);
    SA[jb] = vr[q];      // bf16 row bytes [32q, 32q+16)
    SB[jb] = vr[q + 4];  // bf16 row bytes [64+32q, ...)
  }
  float pvv[48];  // PV rows fp32, addresses independent of softmax -> all in flight
#pragma unroll
  for (int j = 0; j < 48; ++j) pvv[j] = whbase[(size_t)cl[j] * HD + lane];
  float skv = Sk[(size_t)wid * HD + lane];

  // ---------- scores (main 3 blocks) ----------
  float s[5], p[5];
#pragma unroll
  for (int jb = 0; jb < 3; ++jb) {
    uint4 A = SA[jb], B = SB[jb];
    float t = wa0.x * lo16(A.x) + wa0.y * hi16(A.x) + wa0.z * lo16(A.y) + wa0.w * hi16(A.y) +
              wa1.x * lo16(A.z) + wa1.y * hi16(A.z) + wa1.z * lo16(A.w) + wa1.w * hi16(A.w) +
              wb0.x * lo16(B.x) + wb0.y * hi16(B.x) + wb0.z * lo16(B.y) + wb0.w * hi16(B.y) +
              wb1.x * lo16(B.z) + wb1.y * hi16(B.z) + wb1.z * lo16(B.w) + wb1.w * hi16(B.w);
    t += __shfl_xor(t, 1, 64);  // quad butterfly: all 4 lanes hold full dot
    t += __shfl_xor(t, 2, 64);
    s[jb] = (jb * 16 + gq < nn) ? t * 0.125f : -1e30f;
  }
  s[3] = -1e30f;
  s[4] = -1e30f;
  bool tail = (nn > 48);  // wave-uniform
  if (tail) {
#pragma unroll
    for (int jb = 3; jb < 5; ++jb) {
      int j = jb * 16 + gq;
      int m = cl[j];
      const uint4* vr = (const uint4*)(w16base + (size_t)m * HD);
      uint4 A = vr[q];
      uint4 B = vr[q + 4];
      float t = wa0.x * lo16(A.x) + wa0.y * hi16(A.x) + wa0.z * lo16(A.y) + wa0.w * hi16(A.y) +
                wa1.x * lo16(A.z) + wa1.y * hi16(A.z) + wa1.z * lo16(A.w) + wa1.w * hi16(A.w) +
                wb0.x * lo16(B.x) + wb0.y * hi16(B.x) + wb0.z * lo16(B.y) + wb0.w * hi16(B.y) +
                wb1.x * lo16(B.z) + wb1.y * hi16(B.z) + wb1.z * lo16(B.w) + wb1.w * hi16(B.w);
      t += __shfl_xor(t, 1, 64);
      t += __shfl_xor(t, 2, 64);
      s[jb] = (j < nn) ? t * 0.125f : -1e30f;
    }
  }

  // ---------- softmax: 4-step quad-class reduces (s,p are quad-uniform) ----------
  float mx = fmaxf(fmaxf(fmaxf(s[0], s[1]), fmaxf(s[2], s[3])), s[4]);
  mx = fmaxf(mx, __shfl_xor(mx, 4, 64));
  mx = fmaxf(mx, __shfl_xor(mx, 8, 64));
  mx = fmaxf(mx, __shfl_xor(mx, 16, 64));
  mx = fmaxf(mx, __shfl_xor(mx, 32, 64));
  float sum = 0.f;
#pragma unroll
  for (int jb = 0; jb < 5; ++jb) {
    p[jb] = (jb * 16 + gq < nn) ? __expf(s[jb] - mx) : 0.f;
    sum += p[jb];
  }
  sum += __shfl_xor(sum, 4, 64);
  sum += __shfl_xor(sum, 8, 64);
  sum += __shfl_xor(sum, 16, 64);
  sum += __shfl_xor(sum, 32, 64);
  // 4-step reduce counts each j ONCE (one lane per quad-class) -> inv = 1/sum.
  // (r9 bug: used 4/sum, correct only for the 64-lane reduce where each j is counted 4x.)
  float inv = 1.f / sum;

  // ---------- PV: staged values, pure VALU, 4 independent acc chains ----------
  float a0 = 0.f, a1 = 0.f, a2 = 0.f, a3 = 0.f;
#define RL(jb, jj) __int_as_float(__builtin_amdgcn_readlane(__float_as_int(p[jb]), 4 * (jj)))
#pragma unroll
  for (int j = 0; j < 48; j += 4) {
    a0 = fmaf(RL(j / 16, j % 16), pvv[j], a0);
    a1 = fmaf(RL((j + 1) / 16, (j + 1) % 16), pvv[j + 1], a1);
    a2 = fmaf(RL((j + 2) / 16, (j + 2) % 16), pvv[j + 2], a2);
    a3 = fmaf(RL((j + 3) / 16, (j + 3) % 16), pvv[j + 3], a3);
  }
  if (tail) {
#pragma unroll
    for (int jj = 0; jj < 16; ++jj) {
      a0 = fmaf(RL(3, jj), whbase[(size_t)cl[48 + jj] * HD + lane], a0);
      a1 = fmaf(RL(4, jj), whbase[(size_t)cl[64 + jj] * HD + lane], a1);
    }
  }
#undef RL
  float acc = ((a0 + a1) + (a2 + a3)) * inv;

  if (ELU1) {
    float e = acc > 0.f ? acc : (__expf(acc) - 1.f);
    xout[(size_t)wid * HD + lane] = e + skv;
  } else {
    float val = acc + skv;
    float wsum = val * roW[lane];
#pragma unroll
    for (int off = 32; off > 0; off >>= 1) wsum += __shfl_xor(wsum, off, 64);
    if (lane == 0) out[wid] = wsum + rob[0];
  }
}

extern "C" void kernel_launch(void* const* d_in, const int* in_sizes, int n_in,
                              void* d_out, int out_size, void* d_ws, size_t ws_size,
                              hipStream_t stream) {
  const float* stim = (const float*)d_in[0];
  const float* adj  = (const float*)d_in[1];
  const float* W1   = (const float*)d_in[2];
  const float* b1   = (const float*)d_in[3];
  const float* lng  = (const float*)d_in[4];
  const float* lnb  = (const float*)d_in[5];
  const float* W2   = (const float*)d_in[6];
  const float* b2   = (const float*)d_in[7];
  const float* emb  = (const float*)d_in[8];
  const float* Wg1  = (const float*)d_in[9];
  const float* Wg2  = (const float*)d_in[10];
  const float* s1w  = (const float*)d_in[11];
  const float* s1b  = (const float*)d_in[12];
  const float* s2w  = (const float*)d_in[13];
  const float* s2b  = (const float*)d_in[14];
  const float* roW  = (const float*)d_in[15];
  const float* rob  = (const float*)d_in[16];
  float* out = (float*)d_out;

  char* ws = (char*)d_ws;
  float* g    = (float*)(ws + 0);          // 256 f32
  float* part = (float*)(ws + 4096);       // 96 KB
  int*   cnt  = (int*)(ws + 131072);       // 4096 ints
  int*   cols = (int*)(ws + 147456);       // 4096*80 ints = 1.25 MB
  float* Wh   = (float*)(ws + 1572864);    // 4 MB
  float* Sk   = (float*)(ws + 5767168);    // 4 MB
  float* x1   = (float*)(ws + 9961472);    // 4 MB
  u16*   Wh16 = (u16*)(ws + 14155776);     // 2 MB  (total ~16.25 MB)

  enc_a_kernel<<<dim3(24, 4), dim3(256), 0, stream>>>(stim, W1, part);
  enc_b_kernel<<<dim3(4), dim3(128), 0, stream>>>(part, b1, lng, lnb, W2, b2, g);
  csr_kernel<<<dim3(NV), dim3(256), 0, stream>>>(adj, cnt, cols);
  whsk_kernel<1><<<dim3(NB * NV / 32), dim3(256), 0, stream>>>(g, emb, (const float*)nullptr,
                                                               Wg1, s1w, s1b, Wh, Wh16, Sk);
  attn_kernel<true><<<dim3(NB * NV / 4), dim3(256), 0, stream>>>(Wh, Wh16, Sk, cnt, cols, x1,
                                                                 roW, rob, (float*)nullptr);
  whsk_kernel<2><<<dim3(NB * NV / 32), dim3(256), 0, stream>>>(g, emb, x1, Wg2, s2w, s2b,
                                                               Wh, Wh16, Sk);
  attn_kernel<false><<<dim3(NB * NV / 4), dim3(256), 0, stream>>>(Wh, Wh16, Sk, cnt, cols,
                                                                  (float*)nullptr, roW, rob, out);
}

// Round 11
// 89.083 us; speedup vs baseline: 1.1108x; 1.1108x over previous
//
#include <hip/hip_runtime.h>
#include <math.h>

#define NB 4
#define NV 4096
#define DIN 3072
#define HD 64
#define CAP 80

typedef unsigned short u16;
typedef unsigned int u32;

__device__ __forceinline__ float lo16(u32 u) { return __uint_as_float(u << 16); }
__device__ __forceinline__ float hi16(u32 u) { return __uint_as_float(u & 0xffff0000u); }

// ---------------- encoder stage A: partial GEMV h_partial = stim @ W1 over k-chunks
__global__ __launch_bounds__(256) void enc_a_kernel(const float* __restrict__ stim,
                                                    const float* __restrict__ W1,
                                                    float* __restrict__ part) {
  int c = blockIdx.x;           // 24 k-chunks of 128
  int b = blockIdx.y;           // 4 batches
  int t = threadIdx.x;
  int j = t & 127, h = t >> 7;  // h: which 64-k half
  int k0 = c * 128 + h * 64;
  float acc = 0.f;
#pragma unroll 8
  for (int k = 0; k < 64; ++k)
    acc += stim[b * DIN + k0 + k] * W1[(size_t)(k0 + k) * 128 + j];
  part[((b * 24 + c) * 2 + h) * 128 + j] = acc;
}

// ---------------- encoder stage B: fixed-order reduce + LN + GELU + Linear(128->64)
__global__ __launch_bounds__(128) void enc_b_kernel(
    const float* __restrict__ part, const float* __restrict__ b1,
    const float* __restrict__ lng, const float* __restrict__ lnb,
    const float* __restrict__ W2, const float* __restrict__ b2, float* __restrict__ g) {
  int b = blockIdx.x;
  int t = threadIdx.x;
  float hv = 0.f;
  for (int c = 0; c < 48; ++c) hv += part[(b * 48 + c) * 128 + t];  // deterministic order
  hv += b1[t];
  __shared__ float act[128];
  __shared__ float red[128];
  __shared__ float s_mu, s_var;
  act[t] = hv;
  red[t] = hv;
  __syncthreads();
  for (int s = 64; s > 0; s >>= 1) {
    if (t < s) red[t] += red[t + s];
    __syncthreads();
  }
  if (t == 0) s_mu = red[0] * (1.f / 128.f);
  __syncthreads();
  float dv = act[t] - s_mu;
  red[t] = dv * dv;
  __syncthreads();
  for (int s = 64; s > 0; s >>= 1) {
    if (t < s) red[t] += red[t + s];
    __syncthreads();
  }
  if (t == 0) s_var = red[0] * (1.f / 128.f);
  __syncthreads();
  float y = (act[t] - s_mu) * rsqrtf(s_var + 1e-5f) * lng[t] + lnb[t];
  act[t] = 0.5f * y * (1.f + erff(y * 0.70710678118f));  // exact GELU
  __syncthreads();
  if (t < 64) {
    float a2 = 0.f;
    for (int k = 0; k < 128; ++k) a2 += act[k] * W2[k * 64 + t];
    g[b * 64 + t] = a2 + b2[t];
  }
}

// ---------------- deterministic neighbor-list build; shuffle prefix-scan; zero-filled tail
__global__ __launch_bounds__(256) void csr_kernel(const float* __restrict__ adj,
                                                  int* __restrict__ cnt, int* __restrict__ cols) {
  int row = blockIdx.x;
  int t = threadIdx.x;
  int l = t & 63, w = t >> 6;
  __shared__ int wtot[4];
  __shared__ int stot;
  const float4* p = (const float4*)(adj + (size_t)row * NV);
  float4 v0 = p[t], v1 = p[t + 256], v2 = p[t + 512], v3 = p[t + 768];
  int c = (v0.x > 0.f) + (v0.y > 0.f) + (v0.z > 0.f) + (v0.w > 0.f) +
          (v1.x > 0.f) + (v1.y > 0.f) + (v1.z > 0.f) + (v1.w > 0.f) +
          (v2.x > 0.f) + (v2.y > 0.f) + (v2.z > 0.f) + (v2.w > 0.f) +
          (v3.x > 0.f) + (v3.y > 0.f) + (v3.z > 0.f) + (v3.w > 0.f);
  int val = c;  // inclusive prefix within wave
#pragma unroll
  for (int off = 1; off < 64; off <<= 1) {
    int tmp = __shfl_up(val, off, 64);
    if (l >= off) val += tmp;
  }
  if (l == 63) wtot[w] = val;
  __syncthreads();
  int base = 0;
  for (int i = 0; i < w; ++i) base += wtot[i];
  if (t == 255) {
    int s = base + val;
    s = s > CAP ? CAP : s;
    cnt[row] = s;
    stot = s;
  }
  int o = base + (val - c);  // exclusive global prefix
  int* cr = cols + row * CAP;
#define EMIT(vv, jj) if ((vv) > 0.f) { if (o < CAP) cr[o] = (jj); ++o; }
  int j0 = t * 4, j1 = (t + 256) * 4, j2 = (t + 512) * 4, j3 = (t + 768) * 4;
  EMIT(v0.x, j0) EMIT(v0.y, j0 + 1) EMIT(v0.z, j0 + 2) EMIT(v0.w, j0 + 3)
  EMIT(v1.x, j1) EMIT(v1.y, j1 + 1) EMIT(v1.z, j1 + 2) EMIT(v1.w, j1 + 3)
  EMIT(v2.x, j2) EMIT(v2.y, j2 + 1) EMIT(v2.z, j2 + 2) EMIT(v2.w, j2 + 3)
  EMIT(v3.x, j3) EMIT(v3.y, j3 + 1) EMIT(v3.z, j3 + 2) EMIT(v3.w, j3 + 3)
#undef EMIT
  __syncthreads();
  if (t < CAP && t >= stot) cr[t] = 0;  // valid row id; p==0 masks it in attn
}

// ---------------- fused Wh(fp32 + bf16) = x@Wg and Sk = x@Sw + sb
template <int LAYER>
__global__ __launch_bounds__(256) void whsk_kernel(
    const float* __restrict__ g, const float* __restrict__ emb, const float* __restrict__ xin,
    const float* __restrict__ Wg, const float* __restrict__ Sw, const float* __restrict__ Sb,
    float* __restrict__ Wh, u16* __restrict__ Wh16, float* __restrict__ Sk) {
  __shared__ float wg[4096];
  __shared__ float sw[4096];
  __shared__ float xs[2048];
  __shared__ float sbs[64];
  int tid = threadIdx.x;
  for (int i = tid; i < 4096; i += 256) {
    wg[i] = Wg[i];
    sw[i] = Sw[i];
  }
  if (tid < 64) sbs[tid] = Sb[tid];
  int base = blockIdx.x * 32;  // 32 rows per block; all same batch
  int b = base >> 12;
  for (int i = tid; i < 2048; i += 256) {
    int rr = i >> 6, k = i & 63;
    int grow = base + rr;
    if (LAYER == 1) {
      int n = grow & (NV - 1);
      xs[i] = g[b * 64 + k] + emb[(size_t)n * 64 + k];
    } else {
      xs[i] = xin[(size_t)grow * 64 + k];
    }
  }
  __syncthreads();
  int cidx = tid & 63, r0 = tid >> 6;
  for (int rr = r0; rr < 32; rr += 4) {
    float aw = 0.f, as = 0.f;
#pragma unroll
    for (int k = 0; k < 64; ++k) {
      float xv = xs[rr * 64 + k];
      aw += xv * wg[k * 64 + cidx];
      as += xv * sw[k * 64 + cidx];
    }
    int grow = base + rr;
    Wh[(size_t)grow * 64 + cidx] = aw;
    u32 u = __float_as_uint(aw);  // RNE bf16
    Wh16[(size_t)grow * 64 + cidx] = (u16)((u + 0x7fffu + ((u >> 16) & 1u)) >> 16);
    Sk[(size_t)grow * 64 + cidx] = as + sbs[cidx];
  }
}

// ---------------- sparse GAT attention: wave/row; XCD-batch pinned; all-bf16 gathers
// blockIdx swizzle: consecutive bid round-robin across the 8 XCDs (bid&7 = XCD).
// XCD x serves batch x>>1, row-half x&1 -> per-XCD gather hot set = Wh16[b] (2MB) fits 4MB L2.
template <bool ELU1>
__global__ __launch_bounds__(256) void attn_kernel(
    const float* __restrict__ Wh, const u16* __restrict__ Wh16, const float* __restrict__ Sk,
    const int* __restrict__ cnt, const int* __restrict__ cols, float* __restrict__ xout,
    const float* __restrict__ roW, const float* __restrict__ rob, float* __restrict__ out) {
  int tid = threadIdx.x;
  int lane = tid & 63;
  int w = tid >> 6;
  int bid = blockIdx.x;
  int x = bid & 7;    // XCD slot
  int g = bid >> 3;   // 0..511
  int b = x >> 1;     // batch pinned to XCD pair
  int n = __builtin_amdgcn_readfirstlane((x & 1) * 2048 + g * 4 + w);
  int wid = b * NV + n;
  const float* whbase = Wh + (size_t)b * (NV * HD);
  const u16* w16base = Wh16 + (size_t)b * (NV * HD);
  int nn = __builtin_amdgcn_readfirstlane(cnt[n]);
  const int* cl = cols + n * CAP;
  int q = lane & 3;    // lane-in-quad
  int gq = lane >> 2;  // quad 0..15

  // query chunks (fp32, streamed once): elems [8q,8q+8) and [32+8q,32+8q+8)
  const float* qrow = whbase + n * HD;
  float4 wa0 = *(const float4*)(qrow + 8 * q);
  float4 wa1 = *(const float4*)(qrow + 8 * q + 4);
  float4 wb0 = *(const float4*)(qrow + 8 * q + 32);
  float4 wb1 = *(const float4*)(qrow + 8 * q + 36);

  float s[5], p[5];
#define SCORE_BLOCK(jb)                                                                          \
  {                                                                                              \
    int j = (jb) * 16 + gq;                                                                      \
    int m = cl[j];                                                                               \
    const uint4* vr = (const uint4*)(w16base + (size_t)m * HD);                                  \
    uint4 A = vr[q];                                                                             \
    uint4 B = vr[q + 4];                                                                         \
    float t = wa0.x * lo16(A.x) + wa0.y * hi16(A.x) + wa0.z * lo16(A.y) + wa0.w * hi16(A.y) +    \
              wa1.x * lo16(A.z) + wa1.y * hi16(A.z) + wa1.z * lo16(A.w) + wa1.w * hi16(A.w) +    \
              wb0.x * lo16(B.x) + wb0.y * hi16(B.x) + wb0.z * lo16(B.y) + wb0.w * hi16(B.y) +    \
              wb1.x * lo16(B.z) + wb1.y * hi16(B.z) + wb1.z * lo16(B.w) + wb1.w * hi16(B.w);     \
    t += __shfl_xor(t, 1, 64);                                                                   \
    t += __shfl_xor(t, 2, 64);                                                                   \
    s[jb] = (j < nn) ? t * 0.125f : -1e30f;                                                      \
  }

  // first 3 blocks straight-line (cols tail zero-filled -> m=0 dummy, masked by j<nn)
  SCORE_BLOCK(0)
  SCORE_BLOCK(1)
  SCORE_BLOCK(2)
  s[3] = -1e30f;
  s[4] = -1e30f;
  bool tail = (nn > 48);  // wave-uniform
  if (tail) {
    SCORE_BLOCK(3)
    SCORE_BLOCK(4)
  }
#undef SCORE_BLOCK

  // softmax: 4-step quad-class reduces (s,p quad-uniform); each j counted once -> inv = 1/sum
  float mx = fmaxf(fmaxf(fmaxf(s[0], s[1]), fmaxf(s[2], s[3])), s[4]);
  mx = fmaxf(mx, __shfl_xor(mx, 4, 64));
  mx = fmaxf(mx, __shfl_xor(mx, 8, 64));
  mx = fmaxf(mx, __shfl_xor(mx, 16, 64));
  mx = fmaxf(mx, __shfl_xor(mx, 32, 64));
  float sum = 0.f;
#pragma unroll
  for (int jb = 0; jb < 5; ++jb) {
    p[jb] = (jb * 16 + gq < nn) ? __expf(s[jb] - mx) : 0.f;
    sum += p[jb];
  }
  sum += __shfl_xor(sum, 4, 64);
  sum += __shfl_xor(sum, 8, 64);
  sum += __shfl_xor(sum, 16, 64);
  sum += __shfl_xor(sum, 32, 64);
  float inv = 1.f / sum;

  // PV: bf16 rows (2B/lane, L2-resident under pinning), 4 independent acc chains
  float a0 = 0.f, a1 = 0.f, a2 = 0.f, a3 = 0.f;
#define RL(jb, jj) __int_as_float(__builtin_amdgcn_readlane(__float_as_int(p[jb]), 4 * (jj)))
#define PV_ITER(jb, jj, accv)                                                                    \
  {                                                                                              \
    float pv = RL(jb, jj);                                                                       \
    int m = cl[(jb) * 16 + (jj)];                                                                \
    float vv = __uint_as_float((u32)w16base[(size_t)m * HD + lane] << 16);                       \
    accv = fmaf(pv, vv, accv);                                                                   \
  }
#define PV_BLOCK(jb)                                                                             \
  PV_ITER(jb, 0, a0) PV_ITER(jb, 1, a1) PV_ITER(jb, 2, a2) PV_ITER(jb, 3, a3)                    \
  PV_ITER(jb, 4, a0) PV_ITER(jb, 5, a1) PV_ITER(jb, 6, a2) PV_ITER(jb, 7, a3)                    \
  PV_ITER(jb, 8, a0) PV_ITER(jb, 9, a1) PV_ITER(jb, 10, a2) PV_ITER(jb, 11, a3)                  \
  PV_ITER(jb, 12, a0) PV_ITER(jb, 13, a1) PV_ITER(jb, 14, a2) PV_ITER(jb, 15, a3)
  PV_BLOCK(0)
  PV_BLOCK(1)
  PV_BLOCK(2)
  if (tail) {
    PV_BLOCK(3)
    PV_BLOCK(4)
  }
#undef PV_BLOCK
#undef PV_ITER
#undef RL
  float acc = ((a0 + a1) + (a2 + a3)) * inv;

  float skv = Sk[(size_t)wid * HD + lane];
  if (ELU1) {
    float e = acc > 0.f ? acc : (__expf(acc) - 1.f);
    xout[(size_t)wid * HD + lane] = e + skv;
  } else {
    float val = acc + skv;
    float wsum = val * roW[lane];
#pragma unroll
    for (int off = 32; off > 0; off >>= 1) wsum += __shfl_xor(wsum, off, 64);
    if (lane == 0) out[wid] = wsum + rob[0];
  }
}

extern "C" void kernel_launch(void* const* d_in, const int* in_sizes, int n_in,
                              void* d_out, int out_size, void* d_ws, size_t ws_size,
                              hipStream_t stream) {
  const float* stim = (const float*)d_in[0];
  const float* adj  = (const float*)d_in[1];
  const float* W1   = (const float*)d_in[2];
  const float* b1   = (const float*)d_in[3];
  const float* lng  = (const float*)d_in[4];
  const float* lnb  = (const float*)d_in[5];
  const float* W2   = (const float*)d_in[6];
  const float* b2   = (const float*)d_in[7];
  const float* emb  = (const float*)d_in[8];
  const float* Wg1  = (const float*)d_in[9];
  const float* Wg2  = (const float*)d_in[10];
  const float* s1w  = (const float*)d_in[11];
  const float* s1b  = (const float*)d_in[12];
  const float* s2w  = (const float*)d_in[13];
  const float* s2b  = (const float*)d_in[14];
  const float* roW  = (const float*)d_in[15];
  const float* rob  = (const float*)d_in[16];
  float* out = (float*)d_out;

  char* ws = (char*)d_ws;
  float* g    = (float*)(ws + 0);          // 256 f32
  float* part = (float*)(ws + 4096);       // 96 KB
  int*   cnt  = (int*)(ws + 131072);       // 4096 ints
  int*   cols = (int*)(ws + 147456);       // 4096*80 ints = 1.25 MB
  float* Wh   = (float*)(ws + 1572864);    // 4 MB
  float* Sk   = (float*)(ws + 5767168);    // 4 MB
  float* x1   = (float*)(ws + 9961472);    // 4 MB
  u16*   Wh16 = (u16*)(ws + 14155776);     // 2 MB  (total ~16.25 MB)

  enc_a_kernel<<<dim3(24, 4), dim3(256), 0, stream>>>(stim, W1, part);
  enc_b_kernel<<<dim3(4), dim3(128), 0, stream>>>(part, b1, lng, lnb, W2, b2, g);
  csr_kernel<<<dim3(NV), dim3(256), 0, stream>>>(adj, cnt, cols);
  whsk_kernel<1><<<dim3(NB * NV / 32), dim3(256), 0, stream>>>(g, emb, (const float*)nullptr,
                                                               Wg1, s1w, s1b, Wh, Wh16, Sk);
  attn_kernel<true><<<dim3(NB * NV / 4), dim3(256), 0, stream>>>(Wh, Wh16, Sk, cnt, cols, x1,
                                                                 roW, rob, (float*)nullptr);
  whsk_kernel<2><<<dim3(NB * NV / 32), dim3(256), 0, stream>>>(g, emb, x1, Wg2, s2w, s2b,
                                                               Wh, Wh16, Sk);
  attn_kernel<false><<<dim3(NB * NV / 4), dim3(256), 0, stream>>>(Wh, Wh16, Sk, cnt, cols,
                                                                  (float*)nullptr, roW, rob, out);
}